// Round 1
// baseline (12654.410 us; speedup 1.0000x reference)
//
#include <hip/hip_runtime.h>
#include <math.h>

#define M_TOK 6272      // B*N = 32*196
#define DIM   768
#define NHEAD 12
#define DHEAD 64
#define MLPD  3072
#define KC    64

// ---------------- block reduce (256-thread blocks, 4 waves) ----------------
static __device__ __forceinline__ float block_reduce_sum(float s) {
    __shared__ float r[4];
    #pragma unroll
    for (int off = 32; off > 0; off >>= 1) s += __shfl_down(s, off);
    int lane = threadIdx.x & 63, wave = threadIdx.x >> 6;
    if (lane == 0) r[wave] = s;
    __syncthreads();
    if (threadIdx.x == 0) r[0] = r[0] + r[1] + r[2] + r[3];
    __syncthreads();
    s = r[0];
    __syncthreads();          // safe for repeated calls
    return s;
}

// ---------------- LayerNorm: one block per row (768 = 3*256) ----------------
__global__ __launch_bounds__(256) void ln_kernel(
    const float* __restrict__ x, const float* __restrict__ w,
    const float* __restrict__ b, float* __restrict__ out)
{
    int row = blockIdx.x;
    const float* xr = x + (size_t)row * DIM;
    int t = threadIdx.x;
    float v0 = xr[t], v1 = xr[t + 256], v2 = xr[t + 512];
    float mean = block_reduce_sum(v0 + v1 + v2) * (1.f / 768.f);
    float d0 = v0 - mean, d1 = v1 - mean, d2 = v2 - mean;
    float var = block_reduce_sum(d0 * d0 + d1 * d1 + d2 * d2) * (1.f / 768.f);
    float rstd = rsqrtf(var + 1e-5f);
    float* orow = out + (size_t)row * DIM;
    orow[t]       = d0 * rstd * w[t]       + b[t];
    orow[t + 256] = d1 * rstd * w[t + 256] + b[t + 256];
    orow[t + 512] = d2 * rstd * w[t + 512] + b[t + 512];
}

// ---------------- row ||.||^2 (768 per row) ----------------
__global__ __launch_bounds__(256) void rownorm2_kernel(
    const float* __restrict__ X, float* __restrict__ out)
{
    int row = blockIdx.x;
    const float* xr = X + (size_t)row * DIM;
    int t = threadIdx.x;
    float v0 = xr[t], v1 = xr[t + 256], v2 = xr[t + 512];
    float s = block_reduce_sum(v0 * v0 + v1 * v1 + v2 * v2);
    if (t == 0) out[row] = s;
}

// ---------------- fp32 GEMM: C = act(A@B + bias) + resid ----------------
// A: M x K row-major, B: K x N row-major. Tile 128x64, BK=16, 8x4 per thread.
static __device__ __forceinline__ void gemm_body(
    const float* __restrict__ A, const float* __restrict__ B,
    const float* __restrict__ bias, const float* __restrict__ resid,
    float* __restrict__ C, int M, int N, int K, int act)
{
    __shared__ float As[16][128];   // [k][m]
    __shared__ float Bs[16][64];    // [k][n]
    const int bm = blockIdx.y * 128;
    const int bn = blockIdx.x * 64;
    const int tid = threadIdx.x;
    const int tx = tid & 15;        // col group
    const int ty = tid >> 4;        // row group
    float acc[8][4];
    #pragma unroll
    for (int i = 0; i < 8; ++i)
        #pragma unroll
        for (int j = 0; j < 4; ++j) acc[i][j] = 0.f;

    const int a_row = tid >> 1;           // 0..127
    const int a_kp  = (tid & 1) * 8;      // 0 or 8
    const int b_k   = tid >> 4;           // 0..15
    const int b_c   = (tid & 15) * 4;     // 0..60

    for (int k0 = 0; k0 < K; k0 += 16) {
        int grow = bm + a_row;
        float4 a0, a1;
        if (grow < M) {
            const float* ap = A + (size_t)grow * K + (k0 + a_kp);
            a0 = *(const float4*)ap;
            a1 = *(const float4*)(ap + 4);
        } else {
            a0 = make_float4(0.f, 0.f, 0.f, 0.f); a1 = a0;
        }
        float4 bv = *(const float4*)(B + (size_t)(k0 + b_k) * N + (bn + b_c));
        __syncthreads();   // previous tile fully consumed
        As[a_kp + 0][a_row] = a0.x; As[a_kp + 1][a_row] = a0.y;
        As[a_kp + 2][a_row] = a0.z; As[a_kp + 3][a_row] = a0.w;
        As[a_kp + 4][a_row] = a1.x; As[a_kp + 5][a_row] = a1.y;
        As[a_kp + 6][a_row] = a1.z; As[a_kp + 7][a_row] = a1.w;
        *(float4*)&Bs[b_k][b_c] = bv;
        __syncthreads();
        #pragma unroll
        for (int kk = 0; kk < 16; ++kk) {
            float4 af0 = *(const float4*)&As[kk][ty * 8];
            float4 af1 = *(const float4*)&As[kk][ty * 8 + 4];
            float4 bf  = *(const float4*)&Bs[kk][tx * 4];
            float a_[8] = {af0.x, af0.y, af0.z, af0.w, af1.x, af1.y, af1.z, af1.w};
            float b_[4] = {bf.x, bf.y, bf.z, bf.w};
            #pragma unroll
            for (int i = 0; i < 8; ++i)
                #pragma unroll
                for (int j = 0; j < 4; ++j)
                    acc[i][j] = fmaf(a_[i], b_[j], acc[i][j]);
        }
    }
    #pragma unroll
    for (int i = 0; i < 8; ++i) {
        int row = bm + ty * 8 + i;
        if (row < M) {
            #pragma unroll
            for (int j = 0; j < 4; ++j) {
                int col = bn + tx * 4 + j;
                float v = acc[i][j];
                if (bias)  v += bias[col];
                if (act)   v = 0.5f * v * (1.f + erff(v * 0.70710678118654752f)); // exact gelu
                if (resid) v += resid[(size_t)row * N + col];
                C[(size_t)row * N + col] = v;
            }
        }
    }
}

__global__ __launch_bounds__(256) void gemm_kernel(
    const float* __restrict__ A, const float* __restrict__ B,
    const float* __restrict__ bias, const float* __restrict__ resid,
    float* __restrict__ C, int M, int N, int K, int act)
{
    gemm_body(A, B, bias, resid, C, M, N, K, act);
}

// fused Q/K/V: gridDim.z selects weight/output
__global__ __launch_bounds__(256) void gemm_qkv_kernel(
    const float* __restrict__ A,
    const float* __restrict__ B0, const float* __restrict__ B1, const float* __restrict__ B2,
    float* __restrict__ C0, float* __restrict__ C1, float* __restrict__ C2,
    int M, int N, int K)
{
    const float* B = (blockIdx.z == 0) ? B0 : (blockIdx.z == 1) ? B1 : B2;
    float* C       = (blockIdx.z == 0) ? C0 : (blockIdx.z == 1) ? C1 : C2;
    gemm_body(A, B, nullptr, nullptr, C, M, N, K, 0);
}

// ---------------- attention: one block per (batch, head) ----------------
__global__ __launch_bounds__(256) void attn_kernel(
    const float* __restrict__ q, const float* __restrict__ k,
    const float* __restrict__ v, float* __restrict__ o)
{
    __shared__ float Ks[196][65];      // +1 pad: conflict-free lane-major reads
    __shared__ float ps[4][196];
    int bh = blockIdx.x;
    int b = bh / NHEAD, h = bh % NHEAD;
    const size_t bbase = (size_t)b * 196 * DIM + (size_t)h * DHEAD; // + n*768 + d
    for (int e = threadIdx.x; e < 196 * 64; e += 256) {
        int n = e >> 6, d = e & 63;
        Ks[n][d] = k[bbase + (size_t)n * DIM + d];
    }
    __syncthreads();
    int wave = threadIdx.x >> 6, lane = threadIdx.x & 63;
    const float scale = 0.125f;        // 64^-0.5
    for (int qi = wave; qi < 196; qi += 4) {   // 196 = 4*49, uniform trips
        float qv = q[bbase + (size_t)qi * DIM + lane];
        float s0 = 0.f, s1 = 0.f, s2 = 0.f, s3 = 0.f;
        #pragma unroll 8
        for (int d = 0; d < 64; ++d) {
            float qd = __shfl(qv, d);
            s0 = fmaf(qd, Ks[lane][d], s0);
            s1 = fmaf(qd, Ks[lane + 64][d], s1);
            s2 = fmaf(qd, Ks[lane + 128][d], s2);
            if (lane < 4) s3 = fmaf(qd, Ks[lane + 192][d], s3);
        }
        s0 *= scale; s1 *= scale; s2 *= scale; s3 *= scale;
        float m = fmaxf(fmaxf(s0, s1), s2);
        if (lane < 4) m = fmaxf(m, s3);
        #pragma unroll
        for (int off = 32; off > 0; off >>= 1) m = fmaxf(m, __shfl_xor(m, off));
        float e0 = expf(s0 - m), e1 = expf(s1 - m), e2 = expf(s2 - m);
        float e3 = (lane < 4) ? expf(s3 - m) : 0.f;
        float l = e0 + e1 + e2 + e3;
        #pragma unroll
        for (int off = 32; off > 0; off >>= 1) l += __shfl_xor(l, off);
        float inv = 1.f / l;
        ps[wave][lane]       = e0 * inv;
        ps[wave][lane + 64]  = e1 * inv;
        ps[wave][lane + 128] = e2 * inv;
        if (lane < 4) ps[wave][lane + 192] = e3 * inv;
        // P @ V : lane = output dim; V from global (L2-resident)
        const float* vb = v + bbase + lane;
        float o0 = 0.f, o1 = 0.f, o2 = 0.f, o3 = 0.f;
        #pragma unroll 4
        for (int j = 0; j < 196; j += 4) {
            o0 = fmaf(ps[wave][j],     vb[(size_t)j * DIM],       o0);
            o1 = fmaf(ps[wave][j + 1], vb[(size_t)(j + 1) * DIM], o1);
            o2 = fmaf(ps[wave][j + 2], vb[(size_t)(j + 2) * DIM], o2);
            o3 = fmaf(ps[wave][j + 3], vb[(size_t)(j + 3) * DIM], o3);
        }
        o[bbase + (size_t)qi * DIM + lane] = (o0 + o1) + (o2 + o3);
    }
}

// ---------------- k-means ----------------
__global__ __launch_bounds__(256) void transpose_ct(
    const float* __restrict__ C, float* __restrict__ CT)
{
    int i = blockIdx.x * 256 + threadIdx.x;     // 768*64 total
    if (i < DIM * KC) {
        int d = i / KC, c = i % KC;
        CT[i] = C[(size_t)c * DIM + d];
    }
}

// one wave per point; lane = center index; CT staged in LDS in 256-dim chunks
__global__ __launch_bounds__(256) void assign_kernel(
    const float* __restrict__ P, const float* __restrict__ CT,
    const float* __restrict__ cn2, const float* __restrict__ pn2,
    int* __restrict__ labels)
{
    __shared__ float cts[256 * KC];   // 64 KB
    int wave = threadIdx.x >> 6, lane = threadIdx.x & 63;
    int p = blockIdx.x * 4 + wave;
    float acc = 0.f;
    for (int ch = 0; ch < 3; ++ch) {
        __syncthreads();
        for (int e = threadIdx.x; e < 256 * KC / 4; e += 256)
            ((float4*)cts)[e] = ((const float4*)(CT + (size_t)ch * 256 * KC))[e];
        __syncthreads();
        const float* pr = P + (size_t)p * DIM + ch * 256;
        float a0 = 0.f, a1 = 0.f, a2 = 0.f, a3 = 0.f;
        #pragma unroll 4
        for (int kk = 0; kk < 256; kk += 4) {
            a0 = fmaf(pr[kk],     cts[(kk)     * KC + lane], a0);
            a1 = fmaf(pr[kk + 1], cts[(kk + 1) * KC + lane], a1);
            a2 = fmaf(pr[kk + 2], cts[(kk + 2) * KC + lane], a2);
            a3 = fmaf(pr[kk + 3], cts[(kk + 3) * KC + lane], a3);
        }
        acc += (a0 + a1) + (a2 + a3);
    }
    float dist = (pn2[p] - 2.f * acc) + cn2[lane];
    int idx = lane;
    #pragma unroll
    for (int off = 32; off > 0; off >>= 1) {      // argmin, first-index tie-break
        float d2 = __shfl_xor(dist, off);
        int   i2 = __shfl_xor(idx, off);
        if (d2 < dist || (d2 == dist && i2 < idx)) { dist = d2; idx = i2; }
    }
    if (lane == 0) labels[p] = idx;
}

__global__ __launch_bounds__(256) void count_kernel(
    const int* __restrict__ labels, int* __restrict__ cnt)
{
    int c = blockIdx.x;
    int s = 0;
    for (int p = threadIdx.x; p < M_TOK; p += 256) s += (labels[p] == c);
    #pragma unroll
    for (int off = 32; off > 0; off >>= 1) s += __shfl_down(s, off);
    __shared__ int r[4];
    if ((threadIdx.x & 63) == 0) r[threadIdx.x >> 6] = s;
    __syncthreads();
    if (threadIdx.x == 0) cnt[c] = r[0] + r[1] + r[2] + r[3];
}

// deterministic per-center serial scan (matches segment_sum point order)
__global__ __launch_bounds__(128) void update_kernel(
    const float* __restrict__ P, const int* __restrict__ labels,
    const int* __restrict__ cnt, const float* __restrict__ cin,
    float* __restrict__ cout)
{
    __shared__ int labs[M_TOK];
    int c = blockIdx.y;
    int d = blockIdx.x * 128 + threadIdx.x;
    for (int p = threadIdx.x; p < M_TOK; p += 128) labs[p] = labels[p];
    __syncthreads();
    float s = 0.f;
    for (int p = 0; p < M_TOK; ++p)
        if (labs[p] == c) s += P[(size_t)p * DIM + d];
    int n = cnt[c];
    cout[(size_t)c * DIM + d] = (n > 0) ? (s / (float)n) : cin[(size_t)c * DIM + d];
}

__global__ __launch_bounds__(256) void gather_kernel(
    const float* __restrict__ cproj, const int* __restrict__ labels,
    float* __restrict__ out)
{
    int i = blockIdx.x * 256 + threadIdx.x;       // M_TOK*DIM total
    int p = i / DIM, d = i - p * DIM;
    out[i] = cproj[(size_t)labels[p] * DIM + d];
}

// ---------------- host ----------------
extern "C" void kernel_launch(void* const* d_in, const int* in_sizes, int n_in,
                              void* d_out, int out_size, void* d_ws, size_t ws_size,
                              hipStream_t stream)
{
    const float* x    = (const float*)d_in[0];
    const float* ln1w = (const float*)d_in[1];
    const float* ln1b = (const float*)d_in[2];
    const float* wq   = (const float*)d_in[3];
    const float* wk   = (const float*)d_in[4];
    const float* wv   = (const float*)d_in[5];
    const float* wo   = (const float*)d_in[6];
    const float* bo   = (const float*)d_in[7];
    const float* ln2w = (const float*)d_in[8];
    const float* ln2b = (const float*)d_in[9];
    const float* w1   = (const float*)d_in[10];
    const float* b1   = (const float*)d_in[11];
    const float* w2   = (const float*)d_in[12];
    const float* b2   = (const float*)d_in[13];
    const float* ctw  = (const float*)d_in[14];
    const float* ctb  = (const float*)d_in[15];

    const size_t M768 = (size_t)M_TOK * DIM;
    float* ws    = (float*)d_ws;
    float* xbuf  = ws;
    float* qbuf  = xbuf + M768;
    float* kbuf  = qbuf + M768;
    float* vbuf  = kbuf + M768;
    float* obuf  = vbuf + M768;
    float* m1buf = qbuf;                   // aliases q/k/v/o region (M x 3072), disjoint in time
    float* cA    = obuf + M768;
    float* cB    = cA + (size_t)KC * DIM;
    float* CT    = cB + (size_t)KC * DIM;
    float* cproj = CT + (size_t)KC * DIM;
    float* cn2   = cproj + (size_t)KC * DIM;
    float* pn2   = cn2 + KC;
    int*  labels = (int*)(pn2 + M_TOK);
    int*  cnt    = labels + M_TOK;
    float* hbuf  = (float*)d_out;          // reuse output buffer as LN scratch

    hipMemcpyAsync(xbuf, x, M768 * sizeof(float), hipMemcpyDeviceToDevice, stream);

    dim3 blk(256);
    dim3 gN768(DIM / 64, M_TOK / 128);     // 12 x 49
    dim3 gN3072(MLPD / 64, M_TOK / 128);   // 48 x 49
    dim3 gqkv(DIM / 64, M_TOK / 128, 3);

    for (int d = 0; d < 4; ++d) {
        size_t w768 = (size_t)d * DIM * DIM;
        ln_kernel<<<M_TOK, blk, 0, stream>>>(xbuf, ln1w + d * DIM, ln1b + d * DIM, hbuf);
        gemm_qkv_kernel<<<gqkv, blk, 0, stream>>>(hbuf, wq + w768, wk + w768, wv + w768,
                                                  qbuf, kbuf, vbuf, M_TOK, DIM, DIM);
        attn_kernel<<<32 * NHEAD, blk, 0, stream>>>(qbuf, kbuf, vbuf, obuf);
        gemm_kernel<<<gN768, blk, 0, stream>>>(obuf, wo + w768, bo + d * DIM, xbuf, xbuf,
                                               M_TOK, DIM, DIM, 0);
        ln_kernel<<<M_TOK, blk, 0, stream>>>(xbuf, ln2w + d * DIM, ln2b + d * DIM, hbuf);
        gemm_kernel<<<gN3072, blk, 0, stream>>>(hbuf, w1 + (size_t)d * DIM * MLPD,
                                                b1 + d * MLPD, nullptr, m1buf,
                                                M_TOK, MLPD, DIM, 1);
        gemm_kernel<<<gN768, blk, 0, stream>>>(m1buf, w2 + (size_t)d * MLPD * DIM,
                                               b2 + d * DIM, xbuf, xbuf,
                                               M_TOK, DIM, MLPD, 0);
    }

    // ---- k-means on xbuf (points never change) ----
    rownorm2_kernel<<<M_TOK, blk, 0, stream>>>(xbuf, pn2);
    hipMemcpyAsync(cA, xbuf, (size_t)KC * DIM * sizeof(float),
                   hipMemcpyDeviceToDevice, stream);   // centers0 = first 64 points
    float* cin = cA; float* cout = cB;
    for (int it = 0; it < 10; ++it) {
        rownorm2_kernel<<<KC, blk, 0, stream>>>(cin, cn2);
        transpose_ct<<<(KC * DIM + 255) / 256, blk, 0, stream>>>(cin, CT);
        assign_kernel<<<M_TOK / 4, blk, 0, stream>>>(xbuf, CT, cn2, pn2, labels);
        count_kernel<<<KC, blk, 0, stream>>>(labels, cnt);
        update_kernel<<<dim3(DIM / 128, KC), dim3(128), 0, stream>>>(xbuf, labels, cnt, cin, cout);
        float* t = cin; cin = cout; cout = t;
    }
    rownorm2_kernel<<<KC, blk, 0, stream>>>(cin, cn2);
    transpose_ct<<<(KC * DIM + 255) / 256, blk, 0, stream>>>(cin, CT);
    assign_kernel<<<M_TOK / 4, blk, 0, stream>>>(xbuf, CT, cn2, pn2, labels);

    // out = centers[labels] @ ct_w + ct_b  ==  gather of (centers @ ct_w + ct_b)
    gemm_kernel<<<dim3(DIM / 64, 1), blk, 0, stream>>>(cin, ctw, ctb, nullptr, cproj,
                                                       KC, DIM, DIM, 0);
    gather_kernel<<<(M_TOK * DIM) / 256, blk, 0, stream>>>(cproj, labels, (float*)d_out);
}

// Round 2
// 8763.245 us; speedup vs baseline: 1.4440x; 1.4440x over previous
//
#include <hip/hip_runtime.h>
#include <math.h>

#define M_TOK 6272      // B*N = 32*196
#define DIM   768
#define NHEAD 12
#define DHEAD 64
#define MLPD  3072
#define KC    64

typedef __attribute__((ext_vector_type(8))) short bfrag8;   // 8 bf16 (4 VGPRs)
typedef __attribute__((ext_vector_type(4))) float floatx4;  // MFMA C/D

// ---------------- bf16 split helpers ----------------
static __device__ __forceinline__ unsigned short bf16_rne(float x) {
    unsigned int u = __float_as_uint(x);
    unsigned int r = u + 0x7FFFu + ((u >> 16) & 1u);
    return (unsigned short)(r >> 16);
}

// split 8 floats into hi/lo bf16 and store 16B each to LDS
static __device__ __forceinline__ void split8_store(
    const float* v, unsigned short* hdst, unsigned short* ldst)
{
    bfrag8 vh, vl;
    #pragma unroll
    for (int j = 0; j < 8; ++j) {
        unsigned short hi = bf16_rne(v[j]);
        float hif = __uint_as_float((unsigned int)hi << 16);
        vh[j] = (short)hi;
        vl[j] = (short)bf16_rne(v[j] - hif);
    }
    *(bfrag8*)hdst = vh;
    *(bfrag8*)ldst = vl;
}

// ---------------- block reduce (256-thread blocks, 4 waves) ----------------
static __device__ __forceinline__ float block_reduce_sum(float s) {
    __shared__ float r[4];
    #pragma unroll
    for (int off = 32; off > 0; off >>= 1) s += __shfl_down(s, off);
    int lane = threadIdx.x & 63, wave = threadIdx.x >> 6;
    if (lane == 0) r[wave] = s;
    __syncthreads();
    if (threadIdx.x == 0) r[0] = r[0] + r[1] + r[2] + r[3];
    __syncthreads();
    s = r[0];
    __syncthreads();
    return s;
}

// ---------------- LayerNorm: one block per row ----------------
__global__ __launch_bounds__(256) void ln_kernel(
    const float* __restrict__ x, const float* __restrict__ w,
    const float* __restrict__ b, float* __restrict__ out)
{
    int row = blockIdx.x;
    const float* xr = x + (size_t)row * DIM;
    int t = threadIdx.x;
    float v0 = xr[t], v1 = xr[t + 256], v2 = xr[t + 512];
    float mean = block_reduce_sum(v0 + v1 + v2) * (1.f / 768.f);
    float d0 = v0 - mean, d1 = v1 - mean, d2 = v2 - mean;
    float var = block_reduce_sum(d0 * d0 + d1 * d1 + d2 * d2) * (1.f / 768.f);
    float rstd = rsqrtf(var + 1e-5f);
    float* orow = out + (size_t)row * DIM;
    orow[t]       = d0 * rstd * w[t]       + b[t];
    orow[t + 256] = d1 * rstd * w[t + 256] + b[t + 256];
    orow[t + 512] = d2 * rstd * w[t + 512] + b[t + 512];
}

// ---------------- row ||.||^2 ----------------
__global__ __launch_bounds__(256) void rownorm2_kernel(
    const float* __restrict__ X, float* __restrict__ out)
{
    int row = blockIdx.x;
    const float* xr = X + (size_t)row * DIM;
    int t = threadIdx.x;
    float v0 = xr[t], v1 = xr[t + 256], v2 = xr[t + 512];
    float s = block_reduce_sum(v0 * v0 + v1 * v1 + v2 * v2);
    if (t == 0) out[row] = s;
}

// ================= MFMA split-bf16 GEMM =================
// C = act(A@B + bias) + resid.  A: M x K (M=mult of 128), B: K x N row-major.
// Tile 128x128, BK=32. 4 waves, each 64x64 (4x4 tiles of 16x16x32).
// LDS layout: slot s = ((d16>>4)*4 + (k>>3))*16 + (d16&15), 8 bf16 per slot,
// stored in fragment-read order; thread t stages slots 2t,2t+1 (conflict-free
// writes AND reads).
static __device__ __forceinline__ void gemm_mfma_body(
    const float* __restrict__ A, const float* __restrict__ B,
    const float* __restrict__ bias, const float* __restrict__ resid,
    float* __restrict__ C, int N, int K, int act)
{
    __shared__ __align__(16) unsigned short Ah[4096];
    __shared__ __align__(16) unsigned short Al[4096];
    __shared__ __align__(16) unsigned short Bh[4096];
    __shared__ __align__(16) unsigned short Bl[4096];

    const int tid = threadIdx.x;
    const int bm = blockIdx.y * 128, bn = blockIdx.x * 128;
    const int wave = tid >> 6, lane = tid & 63;
    const int wm = (wave >> 1) * 64, wn = (wave & 1) * 64;
    const int lrow = lane & 15, quad = lane >> 4;

    // staging coords: thread t owns (d16 = sm, sm+1) x (k = skq*8 .. +7)
    const int sm  = (tid >> 5) * 16 + 2 * (tid & 7);
    const int skq = (tid >> 3) & 3;
    const float* Arow0 = A + (size_t)(bm + sm) * K + skq * 8;
    const float* Arow1 = Arow0 + K;
    const float* Bbase = B + (size_t)(skq * 8) * N + bn + sm;

    floatx4 acc[4][4];
    #pragma unroll
    for (int i = 0; i < 4; ++i)
        #pragma unroll
        for (int j = 0; j < 4; ++j) acc[i][j] = floatx4{0.f, 0.f, 0.f, 0.f};

    for (int kt = 0; kt < K; kt += 32) {
        float4 a00 = *(const float4*)(Arow0 + kt);
        float4 a01 = *(const float4*)(Arow0 + kt + 4);
        float4 a10 = *(const float4*)(Arow1 + kt);
        float4 a11 = *(const float4*)(Arow1 + kt + 4);
        float2 bv[8];
        #pragma unroll
        for (int j = 0; j < 8; ++j)
            bv[j] = *(const float2*)(Bbase + (size_t)(kt + j) * N);

        __syncthreads();   // previous tile fully consumed
        {
            float a0v[8] = {a00.x, a00.y, a00.z, a00.w, a01.x, a01.y, a01.z, a01.w};
            float a1v[8] = {a10.x, a10.y, a10.z, a10.w, a11.x, a11.y, a11.z, a11.w};
            split8_store(a0v, &Ah[16 * tid], &Al[16 * tid]);
            split8_store(a1v, &Ah[16 * tid + 8], &Al[16 * tid + 8]);
            float b0v[8] = {bv[0].x, bv[1].x, bv[2].x, bv[3].x,
                            bv[4].x, bv[5].x, bv[6].x, bv[7].x};
            float b1v[8] = {bv[0].y, bv[1].y, bv[2].y, bv[3].y,
                            bv[4].y, bv[5].y, bv[6].y, bv[7].y};
            split8_store(b0v, &Bh[16 * tid], &Bl[16 * tid]);
            split8_store(b1v, &Bh[16 * tid + 8], &Bl[16 * tid + 8]);
        }
        __syncthreads();

        bfrag8 afh[4], afl[4], bfh[4], bfl[4];
        #pragma unroll
        for (int mt = 0; mt < 4; ++mt) {
            int base = (((wm >> 4) + mt) * 4 + quad) * 128 + lrow * 8;
            afh[mt] = *(const bfrag8*)&Ah[base];
            afl[mt] = *(const bfrag8*)&Al[base];
        }
        #pragma unroll
        for (int nt = 0; nt < 4; ++nt) {
            int base = (((wn >> 4) + nt) * 4 + quad) * 128 + lrow * 8;
            bfh[nt] = *(const bfrag8*)&Bh[base];
            bfl[nt] = *(const bfrag8*)&Bl[base];
        }
        #pragma unroll
        for (int mt = 0; mt < 4; ++mt)
            #pragma unroll
            for (int nt = 0; nt < 4; ++nt) {
                acc[mt][nt] = __builtin_amdgcn_mfma_f32_16x16x32_bf16(
                    afh[mt], bfh[nt], acc[mt][nt], 0, 0, 0);
                acc[mt][nt] = __builtin_amdgcn_mfma_f32_16x16x32_bf16(
                    afh[mt], bfl[nt], acc[mt][nt], 0, 0, 0);
                acc[mt][nt] = __builtin_amdgcn_mfma_f32_16x16x32_bf16(
                    afl[mt], bfh[nt], acc[mt][nt], 0, 0, 0);
            }
    }

    // epilogue: C/D layout col = lane&15, row = quad*4 + reg
    #pragma unroll
    for (int mt = 0; mt < 4; ++mt)
        #pragma unroll
        for (int r = 0; r < 4; ++r) {
            int row = bm + wm + mt * 16 + quad * 4 + r;
            #pragma unroll
            for (int nt = 0; nt < 4; ++nt) {
                int col = bn + wn + nt * 16 + lrow;
                float v = acc[mt][nt][r];
                if (bias)  v += bias[col];
                if (act)   v = 0.5f * v * (1.f + erff(v * 0.70710678118654752f));
                if (resid) v += resid[(size_t)row * N + col];
                C[(size_t)row * N + col] = v;
            }
        }
}

__global__ __launch_bounds__(256) void gemm_mfma_kernel(
    const float* __restrict__ A, const float* __restrict__ B,
    const float* __restrict__ bias, const float* __restrict__ resid,
    float* __restrict__ C, int N, int K, int act)
{
    gemm_mfma_body(A, B, bias, resid, C, N, K, act);
}

__global__ __launch_bounds__(256) void gemm_qkv_mfma_kernel(
    const float* __restrict__ A,
    const float* __restrict__ B0, const float* __restrict__ B1, const float* __restrict__ B2,
    float* __restrict__ C0, float* __restrict__ C1, float* __restrict__ C2,
    int N, int K)
{
    const float* B = (blockIdx.z == 0) ? B0 : (blockIdx.z == 1) ? B1 : B2;
    float* C       = (blockIdx.z == 0) ? C0 : (blockIdx.z == 1) ? C1 : C2;
    gemm_mfma_body(A, B, nullptr, nullptr, C, N, K, 0);
}

// ---------------- small fp32 GEMM (kept for 64x768 ct projection) ----------------
static __device__ __forceinline__ void gemm_body(
    const float* __restrict__ A, const float* __restrict__ B,
    const float* __restrict__ bias, const float* __restrict__ resid,
    float* __restrict__ C, int M, int N, int K, int act)
{
    __shared__ float As[16][128];
    __shared__ float Bs[16][64];
    const int bm = blockIdx.y * 128;
    const int bn = blockIdx.x * 64;
    const int tid = threadIdx.x;
    const int tx = tid & 15;
    const int ty = tid >> 4;
    float acc[8][4];
    #pragma unroll
    for (int i = 0; i < 8; ++i)
        #pragma unroll
        for (int j = 0; j < 4; ++j) acc[i][j] = 0.f;

    const int a_row = tid >> 1;
    const int a_kp  = (tid & 1) * 8;
    const int b_k   = tid >> 4;
    const int b_c   = (tid & 15) * 4;

    for (int k0 = 0; k0 < K; k0 += 16) {
        int grow = bm + a_row;
        float4 a0, a1;
        if (grow < M) {
            const float* ap = A + (size_t)grow * K + (k0 + a_kp);
            a0 = *(const float4*)ap;
            a1 = *(const float4*)(ap + 4);
        } else {
            a0 = make_float4(0.f, 0.f, 0.f, 0.f); a1 = a0;
        }
        float4 bvv = *(const float4*)(B + (size_t)(k0 + b_k) * N + (bn + b_c));
        __syncthreads();
        As[a_kp + 0][a_row] = a0.x; As[a_kp + 1][a_row] = a0.y;
        As[a_kp + 2][a_row] = a0.z; As[a_kp + 3][a_row] = a0.w;
        As[a_kp + 4][a_row] = a1.x; As[a_kp + 5][a_row] = a1.y;
        As[a_kp + 6][a_row] = a1.z; As[a_kp + 7][a_row] = a1.w;
        *(float4*)&Bs[b_k][b_c] = bvv;
        __syncthreads();
        #pragma unroll
        for (int kk = 0; kk < 16; ++kk) {
            float4 af0 = *(const float4*)&As[kk][ty * 8];
            float4 af1 = *(const float4*)&As[kk][ty * 8 + 4];
            float4 bf  = *(const float4*)&Bs[kk][tx * 4];
            float a_[8] = {af0.x, af0.y, af0.z, af0.w, af1.x, af1.y, af1.z, af1.w};
            float b_[4] = {bf.x, bf.y, bf.z, bf.w};
            #pragma unroll
            for (int i = 0; i < 8; ++i)
                #pragma unroll
                for (int j = 0; j < 4; ++j)
                    acc[i][j] = fmaf(a_[i], b_[j], acc[i][j]);
        }
    }
    #pragma unroll
    for (int i = 0; i < 8; ++i) {
        int row = bm + ty * 8 + i;
        if (row < M) {
            #pragma unroll
            for (int j = 0; j < 4; ++j) {
                int col = bn + tx * 4 + j;
                float v = acc[i][j];
                if (bias)  v += bias[col];
                if (act)   v = 0.5f * v * (1.f + erff(v * 0.70710678118654752f));
                if (resid) v += resid[(size_t)row * N + col];
                C[(size_t)row * N + col] = v;
            }
        }
    }
}

__global__ __launch_bounds__(256) void gemm_kernel(
    const float* __restrict__ A, const float* __restrict__ B,
    const float* __restrict__ bias, const float* __restrict__ resid,
    float* __restrict__ C, int M, int N, int K, int act)
{
    gemm_body(A, B, bias, resid, C, M, N, K, act);
}

// ---------------- attention: block = (qhalf, head, batch) ----------------
// LDS = K-tile only (51 KB -> 3 blocks/CU); P@V via readlane broadcast.
__global__ __launch_bounds__(256) void attn_kernel(
    const float* __restrict__ q, const float* __restrict__ k,
    const float* __restrict__ v, float* __restrict__ o)
{
    __shared__ float Ks[196][65];      // +1 pad: row-indexed reads conflict-free
    int qh = blockIdx.x;               // 0..1  (q rows 98*qh .. 98*qh+97)
    int h  = blockIdx.y;
    int b  = blockIdx.z;
    const size_t bbase = (size_t)b * 196 * DIM + (size_t)h * DHEAD;
    for (int e = threadIdx.x; e < 196 * 64; e += 256) {
        int n = e >> 6, d = e & 63;
        Ks[n][d] = k[bbase + (size_t)n * DIM + d];
    }
    __syncthreads();
    int wave = threadIdx.x >> 6, lane = threadIdx.x & 63;
    const float scale = 0.125f;
    for (int l = wave; l < 98; l += 4) {
        int qi = qh * 98 + l;
        float qv = q[bbase + (size_t)qi * DIM + lane];
        float s0 = 0.f, s1 = 0.f, s2 = 0.f, s3 = 0.f;
        #pragma unroll 8
        for (int d = 0; d < 64; ++d) {
            float qd = __shfl(qv, d);
            s0 = fmaf(qd, Ks[lane][d], s0);
            s1 = fmaf(qd, Ks[lane + 64][d], s1);
            s2 = fmaf(qd, Ks[lane + 128][d], s2);
            if (lane < 4) s3 = fmaf(qd, Ks[lane + 192][d], s3);
        }
        s0 *= scale; s1 *= scale; s2 *= scale; s3 *= scale;
        float m = fmaxf(fmaxf(s0, s1), s2);
        if (lane < 4) m = fmaxf(m, s3);
        #pragma unroll
        for (int off = 32; off > 0; off >>= 1) m = fmaxf(m, __shfl_xor(m, off));
        float e0 = expf(s0 - m), e1 = expf(s1 - m), e2 = expf(s2 - m);
        float e3 = (lane < 4) ? expf(s3 - m) : 0.f;
        float lsum = e0 + e1 + e2 + e3;
        #pragma unroll
        for (int off = 32; off > 0; off >>= 1) lsum += __shfl_xor(lsum, off);
        float inv = 1.f / lsum;
        float p0 = e0 * inv, p1 = e1 * inv, p2 = e2 * inv, p3 = e3 * inv;
        const float* vb = v + bbase + lane;
        float o0 = 0.f, o1 = 0.f, o2 = 0.f, o3 = 0.f;
        #pragma unroll 8
        for (int j = 0; j < 64; ++j) {
            o0 = fmaf(__shfl(p0, j), vb[(size_t)j * DIM], o0);
            o1 = fmaf(__shfl(p1, j), vb[(size_t)(j + 64) * DIM], o1);
            o2 = fmaf(__shfl(p2, j), vb[(size_t)(j + 128) * DIM], o2);
        }
        #pragma unroll
        for (int j = 0; j < 4; ++j)
            o3 = fmaf(__shfl(p3, j), vb[(size_t)(j + 192) * DIM], o3);
        o[bbase + (size_t)qi * DIM + lane] = (o0 + o1) + (o2 + o3);
    }
}

// ---------------- k-means ----------------
__global__ __launch_bounds__(256) void transpose_ct(
    const float* __restrict__ C, float* __restrict__ CT)
{
    int i = blockIdx.x * 256 + threadIdx.x;
    if (i < DIM * KC) {
        int d = i / KC, c = i % KC;
        CT[i] = C[(size_t)c * DIM + d];
    }
}

__global__ __launch_bounds__(256) void assign_kernel(
    const float* __restrict__ P, const float* __restrict__ CT,
    const float* __restrict__ cn2, const float* __restrict__ pn2,
    int* __restrict__ labels)
{
    __shared__ float cts[256 * KC];
    int wave = threadIdx.x >> 6, lane = threadIdx.x & 63;
    int p = blockIdx.x * 4 + wave;
    float acc = 0.f;
    for (int ch = 0; ch < 3; ++ch) {
        __syncthreads();
        for (int e = threadIdx.x; e < 256 * KC / 4; e += 256)
            ((float4*)cts)[e] = ((const float4*)(CT + (size_t)ch * 256 * KC))[e];
        __syncthreads();
        const float* pr = P + (size_t)p * DIM + ch * 256;
        float a0 = 0.f, a1 = 0.f, a2 = 0.f, a3 = 0.f;
        #pragma unroll 4
        for (int kk = 0; kk < 256; kk += 4) {
            a0 = fmaf(pr[kk],     cts[(kk)     * KC + lane], a0);
            a1 = fmaf(pr[kk + 1], cts[(kk + 1) * KC + lane], a1);
            a2 = fmaf(pr[kk + 2], cts[(kk + 2) * KC + lane], a2);
            a3 = fmaf(pr[kk + 3], cts[(kk + 3) * KC + lane], a3);
        }
        acc += (a0 + a1) + (a2 + a3);
    }
    float dist = (pn2[p] - 2.f * acc) + cn2[lane];
    int idx = lane;
    #pragma unroll
    for (int off = 32; off > 0; off >>= 1) {
        float d2 = __shfl_xor(dist, off);
        int   i2 = __shfl_xor(idx, off);
        if (d2 < dist || (d2 == dist && i2 < idx)) { dist = d2; idx = i2; }
    }
    if (lane == 0) labels[p] = idx;
}

__global__ __launch_bounds__(256) void count_kernel(
    const int* __restrict__ labels, int* __restrict__ cnt)
{
    int c = blockIdx.x;
    int s = 0;
    for (int p = threadIdx.x; p < M_TOK; p += 256) s += (labels[p] == c);
    #pragma unroll
    for (int off = 32; off > 0; off >>= 1) s += __shfl_down(s, off);
    __shared__ int r[4];
    if ((threadIdx.x & 63) == 0) r[threadIdx.x >> 6] = s;
    __syncthreads();
    if (threadIdx.x == 0) cnt[c] = r[0] + r[1] + r[2] + r[3];
}

__global__ __launch_bounds__(128) void update_kernel(
    const float* __restrict__ P, const int* __restrict__ labels,
    const int* __restrict__ cnt, const float* __restrict__ cin,
    float* __restrict__ cout)
{
    __shared__ int labs[M_TOK];
    int c = blockIdx.y;
    int d = blockIdx.x * 128 + threadIdx.x;
    for (int p = threadIdx.x; p < M_TOK; p += 128) labs[p] = labels[p];
    __syncthreads();
    float s = 0.f;
    for (int p = 0; p < M_TOK; ++p)
        if (labs[p] == c) s += P[(size_t)p * DIM + d];
    int n = cnt[c];
    cout[(size_t)c * DIM + d] = (n > 0) ? (s / (float)n) : cin[(size_t)c * DIM + d];
}

__global__ __launch_bounds__(256) void gather_kernel(
    const float* __restrict__ cproj, const int* __restrict__ labels,
    float* __restrict__ out)
{
    int i = blockIdx.x * 256 + threadIdx.x;
    int p = i / DIM, d = i - p * DIM;
    out[i] = cproj[(size_t)labels[p] * DIM + d];
}

// ---------------- host ----------------
extern "C" void kernel_launch(void* const* d_in, const int* in_sizes, int n_in,
                              void* d_out, int out_size, void* d_ws, size_t ws_size,
                              hipStream_t stream)
{
    const float* x    = (const float*)d_in[0];
    const float* ln1w = (const float*)d_in[1];
    const float* ln1b = (const float*)d_in[2];
    const float* wq   = (const float*)d_in[3];
    const float* wk   = (const float*)d_in[4];
    const float* wv   = (const float*)d_in[5];
    const float* wo   = (const float*)d_in[6];
    const float* bo   = (const float*)d_in[7];
    const float* ln2w = (const float*)d_in[8];
    const float* ln2b = (const float*)d_in[9];
    const float* w1   = (const float*)d_in[10];
    const float* b1   = (const float*)d_in[11];
    const float* w2   = (const float*)d_in[12];
    const float* b2   = (const float*)d_in[13];
    const float* ctw  = (const float*)d_in[14];
    const float* ctb  = (const float*)d_in[15];

    const size_t M768 = (size_t)M_TOK * DIM;
    float* ws    = (float*)d_ws;
    float* xbuf  = ws;
    float* qbuf  = xbuf + M768;
    float* kbuf  = qbuf + M768;
    float* vbuf  = kbuf + M768;
    float* obuf  = vbuf + M768;
    float* m1buf = qbuf;                   // aliases q/k/v/o region, disjoint in time
    float* cA    = obuf + M768;
    float* cB    = cA + (size_t)KC * DIM;
    float* CT    = cB + (size_t)KC * DIM;
    float* cproj = CT + (size_t)KC * DIM;
    float* cn2   = cproj + (size_t)KC * DIM;
    float* pn2   = cn2 + KC;
    int*  labels = (int*)(pn2 + M_TOK);
    int*  cnt    = labels + M_TOK;
    float* hbuf  = (float*)d_out;          // reuse output buffer as LN scratch

    hipMemcpyAsync(xbuf, x, M768 * sizeof(float), hipMemcpyDeviceToDevice, stream);

    dim3 blk(256);
    dim3 gN768(DIM / 128, M_TOK / 128);        // 6 x 49
    dim3 gN3072(MLPD / 128, M_TOK / 128);      // 24 x 49
    dim3 gqkv(DIM / 128, M_TOK / 128, 3);      // 6 x 49 x 3

    for (int d = 0; d < 4; ++d) {
        size_t w768 = (size_t)d * DIM * DIM;
        ln_kernel<<<M_TOK, blk, 0, stream>>>(xbuf, ln1w + d * DIM, ln1b + d * DIM, hbuf);
        gemm_qkv_mfma_kernel<<<gqkv, blk, 0, stream>>>(hbuf, wq + w768, wk + w768, wv + w768,
                                                       qbuf, kbuf, vbuf, DIM, DIM);
        attn_kernel<<<dim3(2, NHEAD, 32), blk, 0, stream>>>(qbuf, kbuf, vbuf, obuf);
        gemm_mfma_kernel<<<gN768, blk, 0, stream>>>(obuf, wo + w768, bo + d * DIM, xbuf, xbuf,
                                                    DIM, DIM, 0);
        ln_kernel<<<M_TOK, blk, 0, stream>>>(xbuf, ln2w + d * DIM, ln2b + d * DIM, hbuf);
        gemm_mfma_kernel<<<gN3072, blk, 0, stream>>>(hbuf, w1 + (size_t)d * DIM * MLPD,
                                                     b1 + d * MLPD, nullptr, m1buf,
                                                     MLPD, DIM, 1);
        gemm_mfma_kernel<<<gN768, blk, 0, stream>>>(m1buf, w2 + (size_t)d * MLPD * DIM,
                                                    b2 + d * DIM, xbuf, xbuf,
                                                    DIM, MLPD, 0);
    }

    // ---- k-means on xbuf ----
    rownorm2_kernel<<<M_TOK, blk, 0, stream>>>(xbuf, pn2);
    hipMemcpyAsync(cA, xbuf, (size_t)KC * DIM * sizeof(float),
                   hipMemcpyDeviceToDevice, stream);
    float* cin = cA; float* cout = cB;
    for (int it = 0; it < 10; ++it) {
        rownorm2_kernel<<<KC, blk, 0, stream>>>(cin, cn2);
        transpose_ct<<<(KC * DIM + 255) / 256, blk, 0, stream>>>(cin, CT);
        assign_kernel<<<M_TOK / 4, blk, 0, stream>>>(xbuf, CT, cn2, pn2, labels);
        count_kernel<<<KC, blk, 0, stream>>>(labels, cnt);
        update_kernel<<<dim3(DIM / 128, KC), dim3(128), 0, stream>>>(xbuf, labels, cnt, cin, cout);
        float* t = cin; cin = cout; cout = t;
    }
    rownorm2_kernel<<<KC, blk, 0, stream>>>(cin, cn2);
    transpose_ct<<<(KC * DIM + 255) / 256, blk, 0, stream>>>(cin, CT);
    assign_kernel<<<M_TOK / 4, blk, 0, stream>>>(xbuf, CT, cn2, pn2, labels);

    gemm_kernel<<<dim3(DIM / 64, 1), blk, 0, stream>>>(cin, ctw, ctb, nullptr, cproj,
                                                       KC, DIM, DIM, 0);
    gather_kernel<<<(M_TOK * DIM) / 256, blk, 0, stream>>>(cproj, labels, (float*)d_out);
}

// Round 3
// 6053.580 us; speedup vs baseline: 2.0904x; 1.4476x over previous
//
#include <hip/hip_runtime.h>
#include <math.h>

#define M_TOK 6272      // B*N = 32*196
#define DIM   768
#define NHEAD 12
#define DHEAD 64
#define MLPD  3072
#define KC    64

typedef __attribute__((ext_vector_type(8))) short bfrag8;   // 8 bf16 (4 VGPRs)
typedef __attribute__((ext_vector_type(4))) float floatx4;  // MFMA C/D

// ---------------- bf16 split helpers ----------------
static __device__ __forceinline__ unsigned short bf16_rne(float x) {
    unsigned int u = __float_as_uint(x);
    unsigned int r = u + 0x7FFFu + ((u >> 16) & 1u);
    return (unsigned short)(r >> 16);
}

static __device__ __forceinline__ void split8_store(
    const float* v, unsigned short* hdst, unsigned short* ldst)
{
    bfrag8 vh, vl;
    #pragma unroll
    for (int j = 0; j < 8; ++j) {
        unsigned short hi = bf16_rne(v[j]);
        float hif = __uint_as_float((unsigned int)hi << 16);
        vh[j] = (short)hi;
        vl[j] = (short)bf16_rne(v[j] - hif);
    }
    *(bfrag8*)hdst = vh;
    *(bfrag8*)ldst = vl;
}

// ---------------- block reduce (256-thread blocks, 4 waves) ----------------
static __device__ __forceinline__ float block_reduce_sum(float s) {
    __shared__ float r[4];
    #pragma unroll
    for (int off = 32; off > 0; off >>= 1) s += __shfl_down(s, off);
    int lane = threadIdx.x & 63, wave = threadIdx.x >> 6;
    if (lane == 0) r[wave] = s;
    __syncthreads();
    if (threadIdx.x == 0) r[0] = r[0] + r[1] + r[2] + r[3];
    __syncthreads();
    s = r[0];
    __syncthreads();
    return s;
}

// ---------------- LayerNorm: one block per row ----------------
__global__ __launch_bounds__(256) void ln_kernel(
    const float* __restrict__ x, const float* __restrict__ w,
    const float* __restrict__ b, float* __restrict__ out)
{
    int row = blockIdx.x;
    const float* xr = x + (size_t)row * DIM;
    int t = threadIdx.x;
    float v0 = xr[t], v1 = xr[t + 256], v2 = xr[t + 512];
    float mean = block_reduce_sum(v0 + v1 + v2) * (1.f / 768.f);
    float d0 = v0 - mean, d1 = v1 - mean, d2 = v2 - mean;
    float var = block_reduce_sum(d0 * d0 + d1 * d1 + d2 * d2) * (1.f / 768.f);
    float rstd = rsqrtf(var + 1e-5f);
    float* orow = out + (size_t)row * DIM;
    orow[t]       = d0 * rstd * w[t]       + b[t];
    orow[t + 256] = d1 * rstd * w[t + 256] + b[t + 256];
    orow[t + 512] = d2 * rstd * w[t + 512] + b[t + 512];
}

// ---------------- row ||.||^2 ----------------
__global__ __launch_bounds__(256) void rownorm2_kernel(
    const float* __restrict__ X, float* __restrict__ out)
{
    int row = blockIdx.x;
    const float* xr = X + (size_t)row * DIM;
    int t = threadIdx.x;
    float v0 = xr[t], v1 = xr[t + 256], v2 = xr[t + 512];
    float s = block_reduce_sum(v0 * v0 + v1 * v1 + v2 * v2);
    if (t == 0) out[row] = s;
}

// ================= MFMA split-bf16 GEMM =================
static __device__ __forceinline__ void gemm_mfma_body(
    const float* __restrict__ A, const float* __restrict__ B,
    const float* __restrict__ bias, const float* __restrict__ resid,
    float* __restrict__ C, int N, int K, int act)
{
    __shared__ __align__(16) unsigned short Ah[4096];
    __shared__ __align__(16) unsigned short Al[4096];
    __shared__ __align__(16) unsigned short Bh[4096];
    __shared__ __align__(16) unsigned short Bl[4096];

    const int tid = threadIdx.x;
    const int bm = blockIdx.y * 128, bn = blockIdx.x * 128;
    const int wave = tid >> 6, lane = tid & 63;
    const int wm = (wave >> 1) * 64, wn = (wave & 1) * 64;
    const int lrow = lane & 15, quad = lane >> 4;

    const int sm  = (tid >> 5) * 16 + 2 * (tid & 7);
    const int skq = (tid >> 3) & 3;
    const float* Arow0 = A + (size_t)(bm + sm) * K + skq * 8;
    const float* Arow1 = Arow0 + K;
    const float* Bbase = B + (size_t)(skq * 8) * N + bn + sm;

    floatx4 acc[4][4];
    #pragma unroll
    for (int i = 0; i < 4; ++i)
        #pragma unroll
        for (int j = 0; j < 4; ++j) acc[i][j] = floatx4{0.f, 0.f, 0.f, 0.f};

    for (int kt = 0; kt < K; kt += 32) {
        float4 a00 = *(const float4*)(Arow0 + kt);
        float4 a01 = *(const float4*)(Arow0 + kt + 4);
        float4 a10 = *(const float4*)(Arow1 + kt);
        float4 a11 = *(const float4*)(Arow1 + kt + 4);
        float2 bv[8];
        #pragma unroll
        for (int j = 0; j < 8; ++j)
            bv[j] = *(const float2*)(Bbase + (size_t)(kt + j) * N);

        __syncthreads();
        {
            float a0v[8] = {a00.x, a00.y, a00.z, a00.w, a01.x, a01.y, a01.z, a01.w};
            float a1v[8] = {a10.x, a10.y, a10.z, a10.w, a11.x, a11.y, a11.z, a11.w};
            split8_store(a0v, &Ah[16 * tid], &Al[16 * tid]);
            split8_store(a1v, &Ah[16 * tid + 8], &Al[16 * tid + 8]);
            float b0v[8] = {bv[0].x, bv[1].x, bv[2].x, bv[3].x,
                            bv[4].x, bv[5].x, bv[6].x, bv[7].x};
            float b1v[8] = {bv[0].y, bv[1].y, bv[2].y, bv[3].y,
                            bv[4].y, bv[5].y, bv[6].y, bv[7].y};
            split8_store(b0v, &Bh[16 * tid], &Bl[16 * tid]);
            split8_store(b1v, &Bh[16 * tid + 8], &Bl[16 * tid + 8]);
        }
        __syncthreads();

        bfrag8 afh[4], afl[4], bfh[4], bfl[4];
        #pragma unroll
        for (int mt = 0; mt < 4; ++mt) {
            int base = (((wm >> 4) + mt) * 4 + quad) * 128 + lrow * 8;
            afh[mt] = *(const bfrag8*)&Ah[base];
            afl[mt] = *(const bfrag8*)&Al[base];
        }
        #pragma unroll
        for (int nt = 0; nt < 4; ++nt) {
            int base = (((wn >> 4) + nt) * 4 + quad) * 128 + lrow * 8;
            bfh[nt] = *(const bfrag8*)&Bh[base];
            bfl[nt] = *(const bfrag8*)&Bl[base];
        }
        #pragma unroll
        for (int mt = 0; mt < 4; ++mt)
            #pragma unroll
            for (int nt = 0; nt < 4; ++nt) {
                acc[mt][nt] = __builtin_amdgcn_mfma_f32_16x16x32_bf16(
                    afh[mt], bfh[nt], acc[mt][nt], 0, 0, 0);
                acc[mt][nt] = __builtin_amdgcn_mfma_f32_16x16x32_bf16(
                    afh[mt], bfl[nt], acc[mt][nt], 0, 0, 0);
                acc[mt][nt] = __builtin_amdgcn_mfma_f32_16x16x32_bf16(
                    afl[mt], bfh[nt], acc[mt][nt], 0, 0, 0);
            }
    }

    #pragma unroll
    for (int mt = 0; mt < 4; ++mt)
        #pragma unroll
        for (int r = 0; r < 4; ++r) {
            int row = bm + wm + mt * 16 + quad * 4 + r;
            #pragma unroll
            for (int nt = 0; nt < 4; ++nt) {
                int col = bn + wn + nt * 16 + lrow;
                float v = acc[mt][nt][r];
                if (bias)  v += bias[col];
                if (act)   v = 0.5f * v * (1.f + erff(v * 0.70710678118654752f));
                if (resid) v += resid[(size_t)row * N + col];
                C[(size_t)row * N + col] = v;
            }
        }
}

__global__ __launch_bounds__(256) void gemm_mfma_kernel(
    const float* __restrict__ A, const float* __restrict__ B,
    const float* __restrict__ bias, const float* __restrict__ resid,
    float* __restrict__ C, int N, int K, int act)
{
    gemm_mfma_body(A, B, bias, resid, C, N, K, act);
}

__global__ __launch_bounds__(256) void gemm_qkv_mfma_kernel(
    const float* __restrict__ A,
    const float* __restrict__ B0, const float* __restrict__ B1, const float* __restrict__ B2,
    float* __restrict__ C0, float* __restrict__ C1, float* __restrict__ C2,
    int N, int K)
{
    const float* B = (blockIdx.z == 0) ? B0 : (blockIdx.z == 1) ? B1 : B2;
    float* C       = (blockIdx.z == 0) ? C0 : (blockIdx.z == 1) ? C1 : C2;
    gemm_mfma_body(A, B, nullptr, nullptr, C, N, K, 0);
}

// ---------------- small fp32 GEMM (64x768 ct projection) ----------------
static __device__ __forceinline__ void gemm_body(
    const float* __restrict__ A, const float* __restrict__ B,
    const float* __restrict__ bias, const float* __restrict__ resid,
    float* __restrict__ C, int M, int N, int K, int act)
{
    __shared__ float As[16][128];
    __shared__ float Bs[16][64];
    const int bm = blockIdx.y * 128;
    const int bn = blockIdx.x * 64;
    const int tid = threadIdx.x;
    const int tx = tid & 15;
    const int ty = tid >> 4;
    float acc[8][4];
    #pragma unroll
    for (int i = 0; i < 8; ++i)
        #pragma unroll
        for (int j = 0; j < 4; ++j) acc[i][j] = 0.f;

    const int a_row = tid >> 1;
    const int a_kp  = (tid & 1) * 8;
    const int b_k   = tid >> 4;
    const int b_c   = (tid & 15) * 4;

    for (int k0 = 0; k0 < K; k0 += 16) {
        int grow = bm + a_row;
        float4 a0, a1;
        if (grow < M) {
            const float* ap = A + (size_t)grow * K + (k0 + a_kp);
            a0 = *(const float4*)ap;
            a1 = *(const float4*)(ap + 4);
        } else {
            a0 = make_float4(0.f, 0.f, 0.f, 0.f); a1 = a0;
        }
        float4 bvv = *(const float4*)(B + (size_t)(k0 + b_k) * N + (bn + b_c));
        __syncthreads();
        As[a_kp + 0][a_row] = a0.x; As[a_kp + 1][a_row] = a0.y;
        As[a_kp + 2][a_row] = a0.z; As[a_kp + 3][a_row] = a0.w;
        As[a_kp + 4][a_row] = a1.x; As[a_kp + 5][a_row] = a1.y;
        As[a_kp + 6][a_row] = a1.z; As[a_kp + 7][a_row] = a1.w;
        *(float4*)&Bs[b_k][b_c] = bvv;
        __syncthreads();
        #pragma unroll
        for (int kk = 0; kk < 16; ++kk) {
            float4 af0 = *(const float4*)&As[kk][ty * 8];
            float4 af1 = *(const float4*)&As[kk][ty * 8 + 4];
            float4 bf  = *(const float4*)&Bs[kk][tx * 4];
            float a_[8] = {af0.x, af0.y, af0.z, af0.w, af1.x, af1.y, af1.z, af1.w};
            float b_[4] = {bf.x, bf.y, bf.z, bf.w};
            #pragma unroll
            for (int i = 0; i < 8; ++i)
                #pragma unroll
                for (int j = 0; j < 4; ++j)
                    acc[i][j] = fmaf(a_[i], b_[j], acc[i][j]);
        }
    }
    #pragma unroll
    for (int i = 0; i < 8; ++i) {
        int row = bm + ty * 8 + i;
        if (row < M) {
            #pragma unroll
            for (int j = 0; j < 4; ++j) {
                int col = bn + tx * 4 + j;
                float v = acc[i][j];
                if (bias)  v += bias[col];
                if (act)   v = 0.5f * v * (1.f + erff(v * 0.70710678118654752f));
                if (resid) v += resid[(size_t)row * N + col];
                C[(size_t)row * N + col] = v;
            }
        }
    }
}

__global__ __launch_bounds__(256) void gemm_kernel(
    const float* __restrict__ A, const float* __restrict__ B,
    const float* __restrict__ bias, const float* __restrict__ resid,
    float* __restrict__ C, int M, int N, int K, int act)
{
    gemm_body(A, B, bias, resid, C, M, N, K, act);
}

// ---------------- attention: block = (qhalf, head, batch) ----------------
__global__ __launch_bounds__(256) void attn_kernel(
    const float* __restrict__ q, const float* __restrict__ k,
    const float* __restrict__ v, float* __restrict__ o)
{
    __shared__ float Ks[196][65];
    int qh = blockIdx.x;
    int h  = blockIdx.y;
    int b  = blockIdx.z;
    const size_t bbase = (size_t)b * 196 * DIM + (size_t)h * DHEAD;
    for (int e = threadIdx.x; e < 196 * 64; e += 256) {
        int n = e >> 6, d = e & 63;
        Ks[n][d] = k[bbase + (size_t)n * DIM + d];
    }
    __syncthreads();
    int wave = threadIdx.x >> 6, lane = threadIdx.x & 63;
    const float scale = 0.125f;
    for (int l = wave; l < 98; l += 4) {
        int qi = qh * 98 + l;
        float qv = q[bbase + (size_t)qi * DIM + lane];
        float s0 = 0.f, s1 = 0.f, s2 = 0.f, s3 = 0.f;
        #pragma unroll 8
        for (int d = 0; d < 64; ++d) {
            float qd = __shfl(qv, d);
            s0 = fmaf(qd, Ks[lane][d], s0);
            s1 = fmaf(qd, Ks[lane + 64][d], s1);
            s2 = fmaf(qd, Ks[lane + 128][d], s2);
            if (lane < 4) s3 = fmaf(qd, Ks[lane + 192][d], s3);
        }
        s0 *= scale; s1 *= scale; s2 *= scale; s3 *= scale;
        float m = fmaxf(fmaxf(s0, s1), s2);
        if (lane < 4) m = fmaxf(m, s3);
        #pragma unroll
        for (int off = 32; off > 0; off >>= 1) m = fmaxf(m, __shfl_xor(m, off));
        float e0 = expf(s0 - m), e1 = expf(s1 - m), e2 = expf(s2 - m);
        float e3 = (lane < 4) ? expf(s3 - m) : 0.f;
        float lsum = e0 + e1 + e2 + e3;
        #pragma unroll
        for (int off = 32; off > 0; off >>= 1) lsum += __shfl_xor(lsum, off);
        float inv = 1.f / lsum;
        float p0 = e0 * inv, p1 = e1 * inv, p2 = e2 * inv, p3 = e3 * inv;
        const float* vb = v + bbase + lane;
        float o0 = 0.f, o1 = 0.f, o2 = 0.f, o3 = 0.f;
        #pragma unroll 8
        for (int j = 0; j < 64; ++j) {
            o0 = fmaf(__shfl(p0, j), vb[(size_t)j * DIM], o0);
            o1 = fmaf(__shfl(p1, j), vb[(size_t)(j + 64) * DIM], o1);
            o2 = fmaf(__shfl(p2, j), vb[(size_t)(j + 128) * DIM], o2);
        }
        #pragma unroll
        for (int j = 0; j < 4; ++j)
            o3 = fmaf(__shfl(p3, j), vb[(size_t)(j + 192) * DIM], o3);
        o[bbase + (size_t)qi * DIM + lane] = (o0 + o1) + (o2 + o3);
    }
}

// ---------------- k-means ----------------
__global__ __launch_bounds__(256) void transpose_ct(
    const float* __restrict__ C, float* __restrict__ CT)
{
    int i = blockIdx.x * 256 + threadIdx.x;
    if (i < DIM * KC) {
        int d = i / KC, c = i % KC;
        CT[i] = C[(size_t)c * DIM + d];
    }
}

__global__ __launch_bounds__(256) void assign_kernel(
    const float* __restrict__ P, const float* __restrict__ CT,
    const float* __restrict__ cn2, const float* __restrict__ pn2,
    int* __restrict__ labels)
{
    __shared__ float cts[256 * KC];
    int wave = threadIdx.x >> 6, lane = threadIdx.x & 63;
    int p = blockIdx.x * 4 + wave;
    float acc = 0.f;
    for (int ch = 0; ch < 3; ++ch) {
        __syncthreads();
        for (int e = threadIdx.x; e < 256 * KC / 4; e += 256)
            ((float4*)cts)[e] = ((const float4*)(CT + (size_t)ch * 256 * KC))[e];
        __syncthreads();
        const float* pr = P + (size_t)p * DIM + ch * 256;
        float a0 = 0.f, a1 = 0.f, a2 = 0.f, a3 = 0.f;
        #pragma unroll 4
        for (int kk = 0; kk < 256; kk += 4) {
            a0 = fmaf(pr[kk],     cts[(kk)     * KC + lane], a0);
            a1 = fmaf(pr[kk + 1], cts[(kk + 1) * KC + lane], a1);
            a2 = fmaf(pr[kk + 2], cts[(kk + 2) * KC + lane], a2);
            a3 = fmaf(pr[kk + 3], cts[(kk + 3) * KC + lane], a3);
        }
        acc += (a0 + a1) + (a2 + a3);
    }
    float dist = (pn2[p] - 2.f * acc) + cn2[lane];
    int idx = lane;
    #pragma unroll
    for (int off = 32; off > 0; off >>= 1) {
        float d2 = __shfl_xor(dist, off);
        int   i2 = __shfl_xor(idx, off);
        if (d2 < dist || (d2 == dist && i2 < idx)) { dist = d2; idx = i2; }
    }
    if (lane == 0) labels[p] = idx;
}

// counting sort: one block. cnt[c], off[c], stable order[] of point indices.
__global__ __launch_bounds__(256) void order_kernel(
    const int* __restrict__ labels, int* __restrict__ cnt,
    int* __restrict__ off, int* __restrict__ order)
{
    __shared__ int labs[M_TOK];          // 25 KB
    __shared__ int hist[4][KC];
    __shared__ int wstart[4][KC];
    int tid = threadIdx.x;
    for (int p = tid; p < M_TOK; p += 256) labs[p] = labels[p];
    int wave = tid >> 6, lane = tid & 63;
    __syncthreads();
    // count: wave w scans chunk of 1568, lane c counts label c
    const int base = wave * (M_TOK / 4);
    int h = 0;
    for (int i = 0; i < M_TOK / 4; ++i) h += (labs[base + i] == lane);
    hist[wave][lane] = h;
    __syncthreads();
    if (tid == 0) {
        int run = 0;
        for (int c = 0; c < KC; ++c) {
            int h0 = hist[0][c], h1 = hist[1][c], h2 = hist[2][c], h3 = hist[3][c];
            cnt[c] = h0 + h1 + h2 + h3;
            off[c] = run;
            wstart[0][c] = run;
            wstart[1][c] = run + h0;
            wstart[2][c] = run + h0 + h1;
            wstart[3][c] = run + h0 + h1 + h2;
            run += h0 + h1 + h2 + h3;
        }
    }
    __syncthreads();
    // stable fill: lane c of wave w writes its chunk's label-c points in order
    int pos = wstart[wave][lane];
    for (int i = 0; i < M_TOK / 4; ++i) {
        if (labs[base + i] == lane) order[pos++] = base + i;
    }
}

// one block per center; thread = dim; gather only this center's rows.
__global__ __launch_bounds__(768) void update_gather_kernel(
    const float* __restrict__ P, const int* __restrict__ order,
    const int* __restrict__ cnt, const int* __restrict__ off,
    const float* __restrict__ cin, float* __restrict__ cout)
{
    __shared__ int rows[M_TOK];          // worst case 25 KB
    int c = blockIdx.x;
    int n = cnt[c], o = off[c];
    int d = threadIdx.x;
    for (int i = d; i < n; i += 768) rows[i] = order[o + i];
    __syncthreads();
    float a0 = 0.f, a1 = 0.f, a2 = 0.f, a3 = 0.f;
    int i = 0;
    for (; i + 4 <= n; i += 4) {
        a0 += P[(size_t)rows[i]     * DIM + d];
        a1 += P[(size_t)rows[i + 1] * DIM + d];
        a2 += P[(size_t)rows[i + 2] * DIM + d];
        a3 += P[(size_t)rows[i + 3] * DIM + d];
    }
    for (; i < n; ++i) a0 += P[(size_t)rows[i] * DIM + d];
    float s = (a0 + a1) + (a2 + a3);
    cout[(size_t)c * DIM + d] = (n > 0) ? (s / (float)n) : cin[(size_t)c * DIM + d];
}

__global__ __launch_bounds__(256) void gather_kernel(
    const float* __restrict__ cproj, const int* __restrict__ labels,
    float* __restrict__ out)
{
    int i = blockIdx.x * 256 + threadIdx.x;
    int p = i / DIM, d = i - p * DIM;
    out[i] = cproj[(size_t)labels[p] * DIM + d];
}

// ---------------- host ----------------
extern "C" void kernel_launch(void* const* d_in, const int* in_sizes, int n_in,
                              void* d_out, int out_size, void* d_ws, size_t ws_size,
                              hipStream_t stream)
{
    const float* x    = (const float*)d_in[0];
    const float* ln1w = (const float*)d_in[1];
    const float* ln1b = (const float*)d_in[2];
    const float* wq   = (const float*)d_in[3];
    const float* wk   = (const float*)d_in[4];
    const float* wv   = (const float*)d_in[5];
    const float* wo   = (const float*)d_in[6];
    const float* bo   = (const float*)d_in[7];
    const float* ln2w = (const float*)d_in[8];
    const float* ln2b = (const float*)d_in[9];
    const float* w1   = (const float*)d_in[10];
    const float* b1   = (const float*)d_in[11];
    const float* w2   = (const float*)d_in[12];
    const float* b2   = (const float*)d_in[13];
    const float* ctw  = (const float*)d_in[14];
    const float* ctb  = (const float*)d_in[15];

    const size_t M768 = (size_t)M_TOK * DIM;
    float* ws    = (float*)d_ws;
    float* xbuf  = ws;
    float* qbuf  = xbuf + M768;
    float* kbuf  = qbuf + M768;
    float* vbuf  = kbuf + M768;
    float* obuf  = vbuf + M768;
    float* m1buf = qbuf;                   // aliases q/k/v/o region, disjoint in time
    float* cA    = obuf + M768;
    float* cB    = cA + (size_t)KC * DIM;
    float* CT    = cB + (size_t)KC * DIM;
    float* cproj = CT + (size_t)KC * DIM;
    float* cn2   = cproj + (size_t)KC * DIM;
    float* pn2   = cn2 + KC;
    int*  labels = (int*)(pn2 + M_TOK);
    int*  cnt    = labels + M_TOK;
    int*  coff   = cnt + KC;
    int*  order  = coff + KC;
    float* hbuf  = (float*)d_out;          // reuse output buffer as LN scratch

    hipMemcpyAsync(xbuf, x, M768 * sizeof(float), hipMemcpyDeviceToDevice, stream);

    dim3 blk(256);
    dim3 gN768(DIM / 128, M_TOK / 128);        // 6 x 49
    dim3 gN3072(MLPD / 128, M_TOK / 128);      // 24 x 49
    dim3 gqkv(DIM / 128, M_TOK / 128, 3);      // 6 x 49 x 3

    for (int d = 0; d < 4; ++d) {
        size_t w768 = (size_t)d * DIM * DIM;
        ln_kernel<<<M_TOK, blk, 0, stream>>>(xbuf, ln1w + d * DIM, ln1b + d * DIM, hbuf);
        gemm_qkv_mfma_kernel<<<gqkv, blk, 0, stream>>>(hbuf, wq + w768, wk + w768, wv + w768,
                                                       qbuf, kbuf, vbuf, DIM, DIM);
        attn_kernel<<<dim3(2, NHEAD, 32), blk, 0, stream>>>(qbuf, kbuf, vbuf, obuf);
        gemm_mfma_kernel<<<gN768, blk, 0, stream>>>(obuf, wo + w768, bo + d * DIM, xbuf, xbuf,
                                                    DIM, DIM, 0);
        ln_kernel<<<M_TOK, blk, 0, stream>>>(xbuf, ln2w + d * DIM, ln2b + d * DIM, hbuf);
        gemm_mfma_kernel<<<gN3072, blk, 0, stream>>>(hbuf, w1 + (size_t)d * DIM * MLPD,
                                                     b1 + d * MLPD, nullptr, m1buf,
                                                     MLPD, DIM, 1);
        gemm_mfma_kernel<<<gN768, blk, 0, stream>>>(m1buf, w2 + (size_t)d * MLPD * DIM,
                                                    b2 + d * DIM, xbuf, xbuf,
                                                    DIM, MLPD, 0);
    }

    // ---- k-means on xbuf ----
    rownorm2_kernel<<<M_TOK, blk, 0, stream>>>(xbuf, pn2);
    hipMemcpyAsync(cA, xbuf, (size_t)KC * DIM * sizeof(float),
                   hipMemcpyDeviceToDevice, stream);
    float* cin = cA; float* cout = cB;
    for (int it = 0; it < 10; ++it) {
        rownorm2_kernel<<<KC, blk, 0, stream>>>(cin, cn2);
        transpose_ct<<<(KC * DIM + 255) / 256, blk, 0, stream>>>(cin, CT);
        assign_kernel<<<M_TOK / 4, blk, 0, stream>>>(xbuf, CT, cn2, pn2, labels);
        order_kernel<<<1, blk, 0, stream>>>(labels, cnt, coff, order);
        update_gather_kernel<<<KC, dim3(768), 0, stream>>>(xbuf, order, cnt, coff, cin, cout);
        float* t = cin; cin = cout; cout = t;
    }
    rownorm2_kernel<<<KC, blk, 0, stream>>>(cin, cn2);
    transpose_ct<<<(KC * DIM + 255) / 256, blk, 0, stream>>>(cin, CT);
    assign_kernel<<<M_TOK / 4, blk, 0, stream>>>(xbuf, CT, cn2, pn2, labels);

    gemm_kernel<<<dim3(DIM / 64, 1), blk, 0, stream>>>(cin, ctw, ctb, nullptr, cproj,
                                                       KC, DIM, DIM, 0);
    gather_kernel<<<(M_TOK * DIM) / 256, blk, 0, stream>>>(cproj, labels, (float*)d_out);
}